// Round 10
// baseline (1867.686 us; speedup 1.0000x reference)
//
#include <hip/hip_runtime.h>
#include <cstddef>
#include <cstdint>

#define Bn 256
#define Pn 192
#define Mn 321
#define Mp 336     // padded channel dim (multiple of 16)
#define HIDCn 128
#define HIDRn 128
#define HIDSn 8
#define CKn 6
#define SKIPn 24
#define HWn 24
#define Ln 187   // Pn - CKn + 1
#define PTn 7

typedef _Float16 f16;
typedef f16 f16x2 __attribute__((ext_vector_type(2)));
typedef f16 f16x8 __attribute__((ext_vector_type(8)));
typedef float f32x4 __attribute__((ext_vector_type(4)));
typedef float f32x16 __attribute__((ext_vector_type(16)));

__device__ __forceinline__ float rcpf(float x) {
#if defined(__has_builtin) && __has_builtin(__builtin_amdgcn_rcpf)
  return __builtin_amdgcn_rcpf(x);
#else
  return 1.f / x;
#endif
}
// fast sigmoid/tanh via v_exp_f32 + v_rcp_f32 (saturate correctly at +/-inf)
__device__ __forceinline__ float sigmf(float x) { return rcpf(1.f + __expf(-x)); }
__device__ __forceinline__ float tanh_f(float x) {
  float t = __expf(2.f * x);
  return 1.f - 2.f * rcpf(t + 1.f);
}

// async global->LDS 16B copy; dest must be wave-uniform-base + lane*size pattern
__device__ __forceinline__ void gll16(const void* g, void* l) {
#if defined(__has_builtin) && __has_builtin(__builtin_amdgcn_global_load_lds)
  __builtin_amdgcn_global_load_lds((const __attribute__((address_space(1))) void*)g,
                                   (__attribute__((address_space(3))) void*)l, 16, 0, 0);
#else
  *(uint4*)l = *(const uint4*)g;
#endif
}

// lane-ordered position of (co, cc) inside a [coN x 16] f16 tile:
// ct-tile = co>>5 (256 dwords each), lane = (cc>>3)*32 + (co&31), dword (cc>>1)&3.
__device__ __forceinline__ int lanepos(int co, int cc) {
  int ctg = co >> 5, row = co & 31;
  int h = (cc >> 3) & 1, d = (cc >> 1) & 3;
  return ((ctg * 256 + h * 128 + row * 4 + d) << 1) | (cc & 1);
}

// ================= tree weight repack + fp16 cast (lane-ordered) ============
// in: tree_w (NB,4,M,M,K) -> slabs: [slot][k][cib21][lane-ordered 6144] f16
__global__ __launch_bounds__(256) void repack_w(const float* __restrict__ w, f16* __restrict__ out,
                                                int K, int c0, int c1, int c2) {
  int s = blockIdx.z;
  int n = s >> 2, jj = s & 3;
  int blk = c0 + c1 * n + c2 * (n >> 1);
  int kcib = blockIdx.y;
  int k = kcib / 21, cib = kcib - 21 * k;
  int idx = blockIdx.x * 256 + threadIdx.x;  // [0, 6144) source = co*16+cc
  int co = idx >> 4, cc = idx & 15;
  int ci = cib * 16 + cc;
  f16 val = (f16)0.f;
  if (co < Mn && ci < Mn)
    val = (f16)w[(((size_t)(blk * 4 + jj) * Mn + co) * Mn + ci) * K + k];
  out[(((size_t)s * K + k) * 21 + cib) * 6144 + lanepos(co, cc)] = val;
}

// ================= conv2d weight repack -> f16 slab (lane-ordered) ==========
// in: conv1_w (HIDC,1,CK,Mn) -> out [k][cib21][lane-ordered 2048] f16
__global__ __launch_bounds__(256) void repack_c2w(const float* __restrict__ w, f16* __restrict__ out) {
  int idx = blockIdx.x * 256 + threadIdx.x;  // [0, 258048)
  int cc = idx & 15;
  int co = (idx >> 4) & 127;
  int kcib = idx >> 11;  // 0..125
  int k = kcib / 21, cib = kcib - 21 * k;
  int m = cib * 16 + cc;
  f16 v = (f16)0.f;
  if (m < Mn) v = (f16)w[((size_t)co * CKn + k) * Mn + m];
  out[((size_t)(k * 21 + cib)) * 2048 + lanepos(co, cc)] = v;
}

// ================= gru1 input-weight repack -> f16 slab (lane-ordered) ======
// in: gru1_wih (384,128) -> out [k8][lane-ordered 6144] f16
__global__ __launch_bounds__(256) void repack_giw(const float* __restrict__ w, f16* __restrict__ out) {
  int idx = blockIdx.x * 256 + threadIdx.x;  // [0, 49152)
  int cc = idx & 15;
  int co = (idx >> 4) % 384;
  int k = idx / (16 * 384);  // 0..7
  out[(size_t)k * 6144 + lanepos(co, cc)] = (f16)w[(size_t)co * 128 + k * 16 + cc];
}

// ================= deinterleave -> e/o planes (single fp16) =================
__global__ __launch_bounds__(256) void deint_k(const float* __restrict__ x32,
                                               const f16* __restrict__ parent, int Thp,
                                               f16* __restrict__ o, int Th) {
  int b = blockIdx.x, t = blockIdx.y, z = blockIdx.z;
  int c = z >> 1, eo = z & 1;
  int srow = 2 * t + eo;
  size_t ooff = (((size_t)z * Bn + b) * Th + t) * Mp;
  if (x32) {
    const float* xp = x32 + ((size_t)b * Pn + srow) * Mn;
    for (int m = threadIdx.x; m < Mp; m += 256)
      o[ooff + m] = (m < Mn) ? (f16)xp[m] : (f16)0.f;
  } else {
    const uint32_t* ip = (const uint32_t*)(parent + (((size_t)c * Bn + b) * Thp + srow) * Mp);
    uint32_t* op = (uint32_t*)(o + ooff);
    for (int i = threadIdx.x; i < Mp / 2; i += 256) op[i] = ip[i];
  }
}

// ================= MFMA branch conv (2-phase pipelined fp16) =================
// m-tile 64 = 2 batch x 32 t; 256 thr / 4 waves = (batch wm, co-half wc).
// Per-wave shape IDENTICAL to round-9 proven: 1 A-frag + 6 B-frags -> acc[6].
// Smaller block doubles grid -> 4 blocks/CU resident (latency overlap).
// W lane-ordered; async staged 1 step ahead (dbuf); X dbuf per-cib; 1 barrier/step.
// MK 0: leaky   MK 1: out = src*exp(tanh(v))   MK 2: out = src +/- tanh(v) (by z&1)
template <int K, int MK>
__global__ __launch_bounds__(256, 4) void conv_mfma(
    const f16* __restrict__ inz, long in_zs, int Tin,
    const f16* __restrict__ Wb, int wc0, int wc1, int wc2, int wjoff,
    const float* __restrict__ biasb,
    const f16* __restrict__ srcz, long src_zs,
    f16* __restrict__ outz, long out_zs, int Tout) {
  constexpr int PADL = (K == 5) ? 3 : 0;
  constexpr int TWIN = 32 + K - 1;
  constexpr int SLAB = K * 21 * 6144;
  constexpr int NS = 21 * K;
  __shared__ __align__(16) f16 sXs[2][2][40][24];  // dbuf [batch][t-window][ci pad 48B]
  __shared__ __align__(16) f16 sWs[2][6144];       // dbuf lane-ordered W
  int z = blockIdx.z;
  int nnode = z >> 1, j = z & 1;
  int blk = wc0 + wc1 * nnode + wc2 * (nnode >> 1);
  int slot = nnode * 4 + wjoff + j;
  const uint4* inq = (const uint4*)(inz + (size_t)z * in_zs);
  const uint32_t* wsl = (const uint32_t*)(Wb + (size_t)slot * SLAB);
  const float* bias = biasb + (size_t)(blk * 4 + wjoff + j) * Mn;
  int b0 = blockIdx.x * 2;
  int t0 = blockIdx.y * 32;
  int tid = threadIdx.x;
  int lane = tid & 63;
  int wv = tid >> 6;
  int wm = wv & 1, wc = wv >> 1;

  f32x16 acc[6];
#pragma unroll
  for (int i = 0; i < 6; ++i)
#pragma unroll
    for (int q = 0; q < 16; ++q) acc[i][q] = 0.f;

  auto stageX = [&](int cib, int xb) {
    uint32_t* dXu = (uint32_t*)&sXs[xb][0][0][0];
    constexpr int NX4 = 2 * TWIN * 2;
    for (int idx = tid; idx < NX4; idx += 256) {
      int u2 = idx & 1;
      int rr = idx >> 1;
      int tt = rr % TWIN;
      int bl = rr / TWIN;
      int ts = t0 + tt - PADL;
      ts = max(0, min(ts, Tin - 1));
      uint4 v = inq[((((size_t)(b0 + bl)) * Tin + ts) * Mp + cib * 16) / 8 + u2];
      *(uint4*)&dXu[(bl * 40 + tt) * 12 + u2 * 4] = v;
    }
  };
  auto stageW = [&](int s, int wb) {
    int cib = s / K, k = s - cib * K;
    const uint32_t* wp = wsl + ((size_t)(k * 21 + cib)) * 3072;
    uint32_t* dst = (uint32_t*)&sWs[wb][0];
    for (int i = tid; i < 768; i += 256) gll16(wp + i * 4, dst + i * 4);
  };

  stageX(0, 0);
  stageW(0, 0);
  __syncthreads();
  int wb = 0, xb = 0;
#pragma unroll 1
  for (int s = 0; s < NS; ++s) {
    int cib = s / K, k = s - cib * K;
    if (s + 1 < NS) stageW(s + 1, wb ^ 1);
    if (k == K - 1 && cib + 1 < 21) stageX(cib + 1, xb ^ 1);
    f16x8 ah = *(const f16x8*)&sXs[xb][wm][(lane & 31) + k][(lane >> 5) * 8];
    const f16* sw = &sWs[wb][0];
#pragma unroll
    for (int ct = 0; ct < 6; ++ct) {
      f16x8 bw = *(const f16x8*)&sw[((wc * 6 + ct) * 256 + (lane >> 5) * 128 + (lane & 31) * 4) * 2];
      acc[ct] = __builtin_amdgcn_mfma_f32_32x32x16_f16(ah, bw, acc[ct], 0, 0, 0);
    }
    __syncthreads();
    wb ^= 1;
    if (k == K - 1) xb ^= 1;
  }
  // epilogue
  f16* o = outz + (size_t)z * out_zs;
  const f16* s = srcz ? srcz + (size_t)(z ^ 1) * src_zs : nullptr;
#pragma unroll
  for (int ct = 0; ct < 6; ++ct) {
    int co = wc * 192 + ct * 32 + (lane & 31);
    if (co >= Mp) continue;
    float bb = (co < Mn) ? bias[co] : 0.f;
#pragma unroll
    for (int r = 0; r < 16; ++r) {
      int row = (r & 3) + 8 * (r >> 2) + 4 * (lane >> 5);
      int t = t0 + row;
      if (t >= Tout) continue;
      size_t oo = (((size_t)(b0 + wm)) * Tout + t) * Mp + co;
      float res;
      if (co >= Mn) {
        res = 0.f;
      } else {
        float v = acc[ct][r] + bb;
        if constexpr (MK == 0) {
          res = v > 0.f ? v : 0.01f * v;
        } else {
          float sv = (float)s[oo];
          float th = tanh_f(v);
          if constexpr (MK == 1) res = sv * __expf(th);
          else res = (j == 0) ? sv + th : sv - th;
        }
      }
      o[oo] = (f16)res;
    }
  }
}

// ================= final combine: XR = x + interleave(leaves); + fp16 copy ===
__global__ __launch_bounds__(256) void combine_k(const float* __restrict__ x, const f16* __restrict__ lv,
                                                 float* __restrict__ XR, f16* __restrict__ XRh) {
  int b = blockIdx.x, p = blockIdx.y;
  int c = ((p & 1) << 2) | (p & 2) | ((p >> 2) & 1);
  int row = p >> 3;
  size_t li = (((size_t)c * Bn + b) * 24 + row) * Mp;
  size_t xi = ((size_t)b * Pn + p) * Mn;
  size_t hi = ((size_t)b * Pn + p) * Mp;
  for (int m = threadIdx.x; m < Mp; m += 256) {
    if (m < Mn) {
      float v = x[xi + m] + (float)lv[li + m];
      XR[xi + m] = v;
      XRh[hi + m] = (f16)v;
    } else {
      XRh[hi + m] = (f16)0.f;
    }
  }
}

// ================= conv2d via MFMA (2-phase): XRh -> Cch (L,B,HIDC f16) =====
// block: 32 batches x 4 output rows (1 per wave) x 128 co. 126 ksteps.
__global__ __launch_bounds__(256, 4) void conv2d_mfma(
    const f16* __restrict__ xh, const f16* __restrict__ Wh,
    const float* __restrict__ bias, f16* __restrict__ out) {
  __shared__ __align__(16) f16 sXs[2][9][32][24];  // dbuf [t-window][batch][ci pad]
  __shared__ __align__(16) f16 sWs[2][2048];       // dbuf lane-ordered W
  int b0 = blockIdx.x * 32;
  int l0 = blockIdx.y * 4;
  int tid = threadIdx.x;
  int lane = tid & 63;
  int wv = tid >> 6;  // wave = output-row offset 0..3

  f32x16 acc[4];
#pragma unroll
  for (int i = 0; i < 4; ++i)
#pragma unroll
    for (int q = 0; q < 16; ++q) acc[i][q] = 0.f;

  const uint4* xq = (const uint4*)xh;

  auto stageX = [&](int cib, int xb) {
    uint32_t* dXu = (uint32_t*)&sXs[xb][0][0][0];
    for (int idx = tid; idx < 576; idx += 256) {
      int u = idx & 1;
      int rr = idx >> 1;
      int bb = rr & 31, tt = rr >> 5;
      int p = min(l0 + tt, Pn - 1);
      uint4 v = xq[((((size_t)(b0 + bb)) * Pn + p) * Mp + cib * 16) / 8 + u];
      *(uint4*)&dXu[(tt * 32 + bb) * 12 + u * 4] = v;
    }
  };
  auto stageW = [&](int s, int wb) {
    int cib = s / CKn, k = s - cib * CKn;
    const uint32_t* wp = (const uint32_t*)(Wh + ((size_t)(k * 21 + cib)) * 2048);
    uint32_t* dst = (uint32_t*)&sWs[wb][0];
    gll16(wp + tid * 4, dst + tid * 4);  // 256 units, one per thread
  };

  stageX(0, 0);
  stageW(0, 0);
  __syncthreads();
  int wb = 0, xb = 0;
#pragma unroll 1
  for (int s = 0; s < 126; ++s) {
    int cib = s / CKn, k = s - cib * CKn;
    if (s + 1 < 126) stageW(s + 1, wb ^ 1);
    if (k == CKn - 1 && cib + 1 < 21) stageX(cib + 1, xb ^ 1);
    f16x8 ah = *(const f16x8*)&sXs[xb][wv + k][lane & 31][(lane >> 5) * 8];
    const f16* sw = &sWs[wb][0];
#pragma unroll
    for (int ct = 0; ct < 4; ++ct) {
      f16x8 bw = *(const f16x8*)&sw[(ct * 256 + (lane >> 5) * 128 + (lane & 31) * 4) * 2];
      acc[ct] = __builtin_amdgcn_mfma_f32_32x32x16_f16(ah, bw, acc[ct], 0, 0, 0);
    }
    __syncthreads();
    wb ^= 1;
    if (k == CKn - 1) xb ^= 1;
  }
  // epilogue: relu, f16, layout (l*Bn + b)*128 + co
  int l = l0 + wv;
  if (l < Ln) {
#pragma unroll
    for (int ct = 0; ct < 4; ++ct) {
      int co = ct * 32 + (lane & 31);
      float bb = bias[co];
#pragma unroll
      for (int r = 0; r < 16; ++r) {
        int brow = (r & 3) + 8 * (r >> 2) + 4 * (lane >> 5);
        float y = acc[ct][r] + bb;
        out[((size_t)l * Bn + (b0 + brow)) * HIDCn + co] = (f16)(y > 0.f ? y : 0.f);
      }
    }
  }
}

// ================= GRU1 input GEMM via MFMA =================
// A = Cch (47872 x 128 f16), W lane-ordered [k8][6144], out giA f32 (r,384)+bias
__global__ __launch_bounds__(512, 2) void gemm_gi(const f16* __restrict__ A, const f16* __restrict__ Wb,
                                                  const float* __restrict__ bias, float* __restrict__ out) {
  __shared__ __align__(16) f16 sA[128][136];  // 136-half row pad: 16B-aligned rows, 2-way banks
  __shared__ __align__(16) f16 sW[2][6144];
  int r0 = blockIdx.x * 128;
  int tid = threadIdx.x;
  int lane = tid & 63;
  int wv = tid >> 6;
  int wm = wv & 3, wc = wv >> 2;

  // stage A once: 128 rows x 128 halves = 128 x 16 uint4 = 2048 uint4
  const uint4* aq = (const uint4*)(A + (size_t)r0 * 128);
  for (int i = tid; i < 2048; i += 512) {
    int row = i >> 4, u = i & 15;
    *(uint4*)&sA[row][u * 8] = aq[i];
  }
  {
    const uint32_t* wp = (const uint32_t*)Wb;
    uint32_t* dst = (uint32_t*)&sW[0][0];
    for (int i = tid; i < 768; i += 512) gll16(wp + i * 4, dst + i * 4);
  }
  __syncthreads();

  f32x16 acc[6];
#pragma unroll
  for (int i = 0; i < 6; ++i)
#pragma unroll
    for (int q = 0; q < 16; ++q) acc[i][q] = 0.f;

  int wb = 0;
#pragma unroll 1
  for (int k = 0; k < 8; ++k) {
    if (k + 1 < 8) {
      const uint32_t* wp = (const uint32_t*)(Wb + (size_t)(k + 1) * 6144);
      uint32_t* dst = (uint32_t*)&sW[wb ^ 1][0];
      for (int i = tid; i < 768; i += 512) gll16(wp + i * 4, dst + i * 4);
    }
    f16x8 ah = *(const f16x8*)&sA[wm * 32 + (lane & 31)][k * 16 + (lane >> 5) * 8];
    const f16* sw = &sW[wb][0];
#pragma unroll
    for (int ct = 0; ct < 6; ++ct) {
      f16x8 bw = *(const f16x8*)&sw[((wc * 6 + ct) * 256 + (lane >> 5) * 128 + (lane & 31) * 4) * 2];
      acc[ct] = __builtin_amdgcn_mfma_f32_32x32x16_f16(ah, bw, acc[ct], 0, 0, 0);
    }
    __syncthreads();
    wb ^= 1;
  }
#pragma unroll
  for (int ct = 0; ct < 6; ++ct) {
    int c = wc * 192 + ct * 32 + (lane & 31);
    float bb = bias[c];
#pragma unroll
    for (int r = 0; r < 16; ++r) {
      int row = r0 + wm * 32 + (r & 3) + 8 * (r >> 2) + 4 * (lane >> 5);
      out[(size_t)row * 384 + c] = acc[ct][r] + bb;
    }
  }
}

// ================= GRU1 recurrent v5: per-wave columns, 1 raw barrier/step ===
// 8 waves x 16 cols; wave owns r,z,n gates for its cols. A = h broadcast ->
// every MFMA D-row equals the gate vector -> gates per-lane, no LDS round-trip.
// hp double-buffered; raw s_barrier (no vmcnt drain) + 2-step-deep gi prefetch.
__global__ __launch_bounds__(512) void gru1_k(const float* __restrict__ gi, const float* __restrict__ whh,
                                              const float* __restrict__ bhh, float* __restrict__ hout) {
  __shared__ __align__(16) uint32_t hp[2][64];  // h packed f16x2, double-buffered
  int n = blockIdx.x;
  int tid = threadIdx.x;
  int w = tid >> 6, l = tid & 63;
  int colg = l & 15, kg = l >> 4;
  int col = w * 16 + colg;

  // B-frags: wfr[gate][q] over whh row g = gate*128 + col, k = q*32+kg*8..+8
  f16x8 wfr[3][4];
#pragma unroll
  for (int g = 0; g < 3; ++g) {
    const float* wr = whh + (size_t)(g * 128 + col) * 128;
#pragma unroll
    for (int q = 0; q < 4; ++q) {
      const float4* s4 = (const float4*)(wr + q * 32 + kg * 8);
      float4 lo = s4[0], hi = s4[1];
      f16x8 f;
      f[0] = (f16)lo.x; f[1] = (f16)lo.y; f[2] = (f16)lo.z; f[3] = (f16)lo.w;
      f[4] = (f16)hi.x; f[5] = (f16)hi.y; f[6] = (f16)hi.z; f[7] = (f16)hi.w;
      wfr[g][q] = f;
    }
  }
  float bh_r = bhh[col], bh_z = bhh[128 + col], bh_n = bhh[256 + col];
  if (tid < 128) ((uint32_t*)hp)[tid] = 0u;
  float hprev = 0.f;
  // 2-deep gi prefetch slots
  float gA0, gA1, gA2, gB0, gB1, gB2;
  {
    const float* gp = gi + (size_t)n * 384;
    gA0 = gp[col]; gA1 = gp[128 + col]; gA2 = gp[256 + col];
    const float* gq = gi + ((size_t)Bn + n) * 384;
    gB0 = gq[col]; gB1 = gq[128 + col]; gB2 = gq[256 + col];
  }
  __syncthreads();

  auto gstep = [&](int T, float& G0, float& G1, float& G2, int RB) {
    float u0 = G0, u1 = G1, u2 = G2;
    if (T + 2 < Ln) {
      const float* gp = gi + ((size_t)(T + 2) * Bn + n) * 384;
      G0 = gp[col]; G1 = gp[128 + col]; G2 = gp[256 + col];
    }
    f32x4 ac0{}, ac1{}, ac2{};
#pragma unroll
    for (int q = 0; q < 4; ++q) {
      f16x8 af = __builtin_bit_cast(f16x8, *(const uint4*)&hp[RB][q * 16 + kg * 4]);
      ac0 = __builtin_amdgcn_mfma_f32_16x16x32_f16(af, wfr[0][q], ac0, 0, 0, 0);
      ac1 = __builtin_amdgcn_mfma_f32_16x16x32_f16(af, wfr[1][q], ac1, 0, 0, 0);
      ac2 = __builtin_amdgcn_mfma_f32_16x16x32_f16(af, wfr[2][q], ac2, 0, 0, 0);
    }
    float rg = sigmf(u0 + bh_r + ac0[0]);
    float zg = sigmf(u1 + bh_z + ac1[0]);
    float ng = tanh_f(u2 + bh_n + rg * ac2[0]);
    float hnew = (1.f - zg) * ng + zg * hprev;
    hprev = hnew;
    float other = __shfl_xor(hnew, 1, 64);
    if (l < 16 && !(l & 1)) {
      f16 a = (f16)hnew, b2 = (f16)other;
      hp[RB ^ 1][w * 8 + (l >> 1)] = (uint32_t)__builtin_bit_cast(unsigned short, a) |
                                     ((uint32_t)__builtin_bit_cast(unsigned short, b2) << 16);
    }
    asm volatile("s_waitcnt lgkmcnt(0)" ::: "memory");
    __builtin_amdgcn_s_barrier();
    asm volatile("" ::: "memory");
  };

#pragma unroll 1
  for (int t = 0; t + 1 < Ln; t += 2) {
    gstep(t, gA0, gA1, gA2, 0);
    gstep(t + 1, gB0, gB1, gB2, 1);
  }
  gstep(Ln - 1, gA0, gA1, gA2, 0);  // Ln odd: final step reads hp[0]
  if (l < 16) hout[(size_t)n * 128 + col] = hprev;
}

// ================= skip-GRU input gemm (f16 Cc) =================
__global__ __launch_bounds__(256) void gis_k(const f16* __restrict__ cc, const float* __restrict__ wih,
                                             const float* __restrict__ bih, float* __restrict__ gi) {
  __shared__ float sx[24 * 128];
  int t = blockIdx.x, b = blockIdx.y;
  int tid = threadIdx.x;
  for (int idx = tid; idx < 24 * 128; idx += 256) {
    int sk = idx >> 7, i = idx & 127;
    int l = 19 + t * 24 + sk;
    sx[idx] = (float)cc[((size_t)l * Bn + b) * HIDCn + i];
  }
  __syncthreads();
  for (int idx = tid; idx < 576; idx += 256) {
    int sk = idx / 24, g = idx - sk * 24;
    float a = bih[g];
    for (int i = 0; i < 128; ++i) a = fmaf(sx[sk * 128 + i], wih[g * 128 + i], a);
    gi[((size_t)t * (Bn * SKIPn) + b * 24 + sk) * 24 + g] = a;
  }
}

// ================= skip-GRU recurrent =================
__global__ __launch_bounds__(256) void grus_k(const float* __restrict__ gi, const float* __restrict__ whh,
                                              const float* __restrict__ bhh, float* __restrict__ hout) {
  __shared__ float sw[24 * 8];
  __shared__ float sb[24];
  int tid = threadIdx.x;
  int n = blockIdx.x * 256 + tid;
  if (tid < 192) sw[tid] = whh[tid];
  if (tid < 24) sb[tid] = bhh[tid];
  __syncthreads();
  float h[8];
#pragma unroll
  for (int jj = 0; jj < 8; ++jj) h[jj] = 0.f;
  for (int t = 0; t < PTn; ++t) {
    const float* gir = gi + ((size_t)t * (Bn * SKIPn) + n) * 24;
    float gh[24];
#pragma unroll
    for (int g = 0; g < 24; ++g) {
      float a = sb[g];
#pragma unroll
      for (int jj = 0; jj < 8; ++jj) a = fmaf(sw[g * 8 + jj], h[jj], a);
      gh[g] = a;
    }
#pragma unroll
    for (int jj = 0; jj < 8; ++jj) {
      float rg = sigmf(gir[jj] + gh[jj]);
      float zg = sigmf(gir[8 + jj] + gh[8 + jj]);
      float ng = tanh_f(gir[16 + jj] + rg * gh[16 + jj]);
      h[jj] = (1.f - zg) * ng + zg * h[jj];
    }
  }
#pragma unroll
  for (int jj = 0; jj < 8; ++jj) hout[(size_t)n * 8 + jj] = h[jj];
}

// ================= final linear + highway =================
__global__ __launch_bounds__(384) void final_k(const float* __restrict__ h1, const float* __restrict__ hsb,
                                               const float* __restrict__ lw, const float* __restrict__ lb,
                                               const float* __restrict__ xr, const float* __restrict__ hww,
                                               const float* __restrict__ hwb, float* __restrict__ out) {
  __shared__ float sr[320];
  __shared__ float shw[24];
  int b = blockIdx.x;
  int tid = threadIdx.x;
  if (tid < 128) sr[tid] = h1[(size_t)b * 128 + tid];
  else if (tid < 320) sr[tid] = hsb[(size_t)b * 192 + (tid - 128)];
  if (tid >= 320 && tid < 344) shw[tid - 320] = hww[tid - 320];
  __syncthreads();
  int m = tid;
  if (m >= Mn) return;
  float a = lb[m];
  const float* wr = lw + (size_t)m * 320;
  for (int c = 0; c < 320; ++c) a = fmaf(sr[c], wr[c], a);
  float z = hwb[0];
  const float* xrr = xr + ((size_t)b * Pn + (Pn - HWn)) * Mn + m;
#pragma unroll
  for (int k = 0; k < HWn; ++k) z = fmaf(xrr[(size_t)k * Mn], shw[k], z);
  out[(size_t)b * Mn + m] = a + z;
}

extern "C" void kernel_launch(void* const* d_in, const int* in_sizes, int n_in,
                              void* d_out, int out_size, void* d_ws, size_t ws_size,
                              hipStream_t stream) {
  const float* x = (const float*)d_in[0];
  const float* tw1 = (const float*)d_in[1];
  const float* tb1 = (const float*)d_in[2];
  const float* tw2 = (const float*)d_in[3];
  const float* tb2 = (const float*)d_in[4];
  const float* c1w = (const float*)d_in[5];
  const float* c1b = (const float*)d_in[6];
  const float* g1wih = (const float*)d_in[7];
  const float* g1whh = (const float*)d_in[8];
  const float* g1bih = (const float*)d_in[9];
  const float* g1bhh = (const float*)d_in[10];
  const float* gswih = (const float*)d_in[11];
  const float* gswhh = (const float*)d_in[12];
  const float* gsbih = (const float*)d_in[13];
  const float* gsbhh = (const float*)d_in[14];
  const float* l1w = (const float*)d_in[15];
  const float* l1b = (const float*)d_in[16];
  const float* hww = (const float*)d_in[17];
  const float* hwb = (const float*)d_in[18];
  float* out = (float*)d_out;

  // ---------- workspace plan (~214 MB) ----------
  const size_t Ah = 17891328ull, Bh = 17891328ull, Ch = 17203200ull;  // halves per plane
  f16* Aq = (f16*)d_ws;
  f16* Bq = Aq + Ah;
  f16* Cq = Bq + Bh;
  f16* Wl1 = Cq + Ch;                      // 16*5*21*6144 = 10,321,920 halves
  f16* Wl2 = Wl1 + 10321920ull;            // 16*3*21*6144 = 6,193,152 halves
  f16* Wc2 = (f16*)(Wl2 + 6193152ull);     // conv2d f16 weight slab (258,048 halves)
  f16* Wgi = Wc2 + 258048ull;              // gru1 wih f16 slab (49,152 halves; fits pre-giA gap)
  float* giA = (float*)(Wl2 + 6193152ull) + 246528ull;  // 18,382,848 floats (offset as before)
  float* h1 = giA + 18382848ull;
  float* hsb = h1 + (size_t)Bn * HIDRn;
  float* gis = hsb + (size_t)Bn * SKIPn * HIDSn;
  // post-tree aliases
  float* XR = (float*)Bq;                  // 63.1 MB spanning B + part of C
  f16* Cch = Aq;                           // 12.25 MB f16 conv2d output in A
  f16* XRh = Wl1;                          // fp16 XR, B*P*Mp = 16,515,072 halves == Wl1+Wl2

  // region schedule (validated round 3): per level {EO, S1, CD, S3, EU}
  f16* EO[3] = {Aq, Aq, Bq};
  f16* S1[3] = {Bq, Cq, Aq};
  f16* CD[3] = {Cq, Bq, Cq};
  f16* S3[3] = {Aq, Aq, Bq};
  f16* EU[3] = {Bq, Cq, Aq};
  const int WC0[3] = {0, 1, 2}, WC1[3] = {0, 3, 1}, WC2[3] = {0, 0, 1};

  repack_c2w<<<dim3(1008), 256, 0, stream>>>(c1w, Wc2);
  repack_giw<<<dim3(192), 256, 0, stream>>>(g1wih, Wgi);

  for (int L = 0; L < 3; ++L) {
    int NL = 1 << L;
    int Th = 96 >> L;
    int Z = 2 * NL;
    long zsEO = (long)Bn * Th * Mp;
    long zsS1 = (long)Bn * (Th + 2) * Mp;
    repack_w<<<dim3(24, 5 * 21, NL * 4), 256, 0, stream>>>(tw1, Wl1, 5, WC0[L], WC1[L], WC2[L]);
    repack_w<<<dim3(24, 3 * 21, NL * 4), 256, 0, stream>>>(tw2, Wl2, 3, WC0[L], WC1[L], WC2[L]);
    if (L == 0)
      deint_k<<<dim3(Bn, Th, 2), 256, 0, stream>>>(x, nullptr, 0, EO[0], Th);
    else
      deint_k<<<dim3(Bn, Th, Z), 256, 0, stream>>>(nullptr, EU[L - 1], 2 * Th, EO[L], Th);
    int ty1 = (Th + 2 + 31) / 32, ty2 = (Th + 31) / 32;
    conv_mfma<5, 0><<<dim3(Bn / 2, ty1, Z), 256, 0, stream>>>(
        EO[L], zsEO, Th, Wl1, WC0[L], WC1[L], WC2[L], 0, tb1,
        nullptr, 0, S1[L], zsS1, Th + 2);
    conv_mfma<3, 1><<<dim3(Bn / 2, ty2, Z), 256, 0, stream>>>(
        S1[L], zsS1, Th + 2, Wl2, WC0[L], WC1[L], WC2[L], 0, tb2,
        EO[L], zsEO, CD[L], zsEO, Th);
    conv_mfma<5, 0><<<dim3(Bn / 2, ty1, Z), 256, 0, stream>>>(
        CD[L], zsEO, Th, Wl1, WC0[L], WC1[L], WC2[L], 2, tb1,
        nullptr, 0, S3[L], zsS1, Th + 2);
    conv_mfma<3, 2><<<dim3(Bn / 2, ty2, Z), 256, 0, stream>>>(
        S3[L], zsS1, Th + 2, Wl2, WC0[L], WC1[L], WC2[L], 2, tb2,
        CD[L], zsEO, EU[L], zsEO, Th);
  }

  combine_k<<<dim3(Bn, Pn), 256, 0, stream>>>(x, EU[2], XR, XRh);

  conv2d_mfma<<<dim3(Bn / 32, (Ln + 3) / 4), 256, 0, stream>>>(XRh, Wc2, c1b, Cch);
  gemm_gi<<<dim3((Ln * Bn) / 128), 512, 0, stream>>>(Cch, Wgi, g1bih, giA);
  gru1_k<<<dim3(Bn), 512, 0, stream>>>(giA, g1whh, g1bhh, h1);
  gis_k<<<dim3(PTn, Bn), 256, 0, stream>>>(Cch, gswih, gsbih, gis);
  grus_k<<<dim3((Bn * SKIPn) / 256), 256, 0, stream>>>(gis, gswhh, gsbhh, hsb);
  final_k<<<dim3(Bn), 384, 0, stream>>>(h1, hsb, l1w, l1b, XR, hww, hwb, out);
}

// Round 11
// 1750.827 us; speedup vs baseline: 1.0667x; 1.0667x over previous
//
#include <hip/hip_runtime.h>
#include <cstddef>
#include <cstdint>

#define Bn 256
#define Pn 192
#define Mn 321
#define Mp 336     // padded channel dim (multiple of 16)
#define HIDCn 128
#define HIDRn 128
#define HIDSn 8
#define CKn 6
#define SKIPn 24
#define HWn 24
#define Ln 187   // Pn - CKn + 1
#define PTn 7

typedef _Float16 f16;
typedef f16 f16x2 __attribute__((ext_vector_type(2)));
typedef f16 f16x8 __attribute__((ext_vector_type(8)));
typedef float f32x4 __attribute__((ext_vector_type(4)));
typedef float f32x16 __attribute__((ext_vector_type(16)));

__device__ __forceinline__ float rcpf(float x) {
#if defined(__has_builtin) && __has_builtin(__builtin_amdgcn_rcpf)
  return __builtin_amdgcn_rcpf(x);
#else
  return 1.f / x;
#endif
}
// fast sigmoid/tanh via v_exp_f32 + v_rcp_f32 (saturate correctly at +/-inf)
__device__ __forceinline__ float sigmf(float x) { return rcpf(1.f + __expf(-x)); }
__device__ __forceinline__ float tanh_f(float x) {
  float t = __expf(2.f * x);
  return 1.f - 2.f * rcpf(t + 1.f);
}

// async global->LDS 16B copy; dest must be wave-uniform-base + lane*size pattern
__device__ __forceinline__ void gll16(const void* g, void* l) {
#if defined(__has_builtin) && __has_builtin(__builtin_amdgcn_global_load_lds)
  __builtin_amdgcn_global_load_lds((const __attribute__((address_space(1))) void*)g,
                                   (__attribute__((address_space(3))) void*)l, 16, 0, 0);
#else
  *(uint4*)l = *(const uint4*)g;
#endif
}

// lane-ordered position of (co, cc) inside a [coN x 16] f16 tile:
// ct-tile = co>>5 (256 dwords each), lane = (cc>>3)*32 + (co&31), dword (cc>>1)&3.
__device__ __forceinline__ int lanepos(int co, int cc) {
  int ctg = co >> 5, row = co & 31;
  int h = (cc >> 3) & 1, d = (cc >> 1) & 3;
  return ((ctg * 256 + h * 128 + row * 4 + d) << 1) | (cc & 1);
}

// ================= tree weight repack + fp16 cast (lane-ordered) ============
// in: tree_w (NB,4,M,M,K) -> slabs: [slot][k][cib21][lane-ordered 6144] f16
__global__ __launch_bounds__(256) void repack_w(const float* __restrict__ w, f16* __restrict__ out,
                                                int K, int c0, int c1, int c2) {
  int s = blockIdx.z;
  int n = s >> 2, jj = s & 3;
  int blk = c0 + c1 * n + c2 * (n >> 1);
  int kcib = blockIdx.y;
  int k = kcib / 21, cib = kcib - 21 * k;
  int idx = blockIdx.x * 256 + threadIdx.x;  // [0, 6144) source = co*16+cc
  int co = idx >> 4, cc = idx & 15;
  int ci = cib * 16 + cc;
  f16 val = (f16)0.f;
  if (co < Mn && ci < Mn)
    val = (f16)w[(((size_t)(blk * 4 + jj) * Mn + co) * Mn + ci) * K + k];
  out[(((size_t)s * K + k) * 21 + cib) * 6144 + lanepos(co, cc)] = val;
}

// ================= conv2d weight repack -> f16 slab (lane-ordered) ==========
// in: conv1_w (HIDC,1,CK,Mn) -> out [k][cib21][lane-ordered 2048] f16
__global__ __launch_bounds__(256) void repack_c2w(const float* __restrict__ w, f16* __restrict__ out) {
  int idx = blockIdx.x * 256 + threadIdx.x;  // [0, 258048)
  int cc = idx & 15;
  int co = (idx >> 4) & 127;
  int kcib = idx >> 11;  // 0..125
  int k = kcib / 21, cib = kcib - 21 * k;
  int m = cib * 16 + cc;
  f16 v = (f16)0.f;
  if (m < Mn) v = (f16)w[((size_t)co * CKn + k) * Mn + m];
  out[((size_t)(k * 21 + cib)) * 2048 + lanepos(co, cc)] = v;
}

// ================= gru1 input-weight repack -> f16 slab (lane-ordered) ======
// in: gru1_wih (384,128) -> out [k8][lane-ordered 6144] f16
__global__ __launch_bounds__(256) void repack_giw(const float* __restrict__ w, f16* __restrict__ out) {
  int idx = blockIdx.x * 256 + threadIdx.x;  // [0, 49152)
  int cc = idx & 15;
  int co = (idx >> 4) % 384;
  int k = idx / (16 * 384);  // 0..7
  out[(size_t)k * 6144 + lanepos(co, cc)] = (f16)w[(size_t)co * 128 + k * 16 + cc];
}

// ================= deinterleave -> e/o planes (single fp16) =================
__global__ __launch_bounds__(256) void deint_k(const float* __restrict__ x32,
                                               const f16* __restrict__ parent, int Thp,
                                               f16* __restrict__ o, int Th) {
  int b = blockIdx.x, t = blockIdx.y, z = blockIdx.z;
  int c = z >> 1, eo = z & 1;
  int srow = 2 * t + eo;
  size_t ooff = (((size_t)z * Bn + b) * Th + t) * Mp;
  if (x32) {
    const float* xp = x32 + ((size_t)b * Pn + srow) * Mn;
    for (int m = threadIdx.x; m < Mp; m += 256)
      o[ooff + m] = (m < Mn) ? (f16)xp[m] : (f16)0.f;
  } else {
    const uint32_t* ip = (const uint32_t*)(parent + (((size_t)c * Bn + b) * Thp + srow) * Mp);
    uint32_t* op = (uint32_t*)(o + ooff);
    for (int i = threadIdx.x; i < Mp / 2; i += 256) op[i] = ip[i];
  }
}

// ================= MFMA branch conv (counted-vmcnt pipelined fp16) ==========
// m-tile 128 = 4 batch x 32 t; co 384 over 2 wave-halves; 512 thr / 8 waves.
// r9-proven wave shape (1 A + 6 B reads -> acc[6]); W now in a 3-buffer
// rotation staged 2 steps ahead; ONE raw barrier per step at TOP; counted
// s_waitcnt vmcnt(N) at bottom (N = this wave's just-issued gll16 count) so
// next-next W stays in flight across the barrier (T3/T4).
// MK 0: leaky   MK 1: out = src*exp(tanh(v))   MK 2: out = src +/- tanh(v) (by z&1)
template <int K, int MK>
__global__ __launch_bounds__(512, 2) void conv_mfma(
    const f16* __restrict__ inz, long in_zs, int Tin,
    const f16* __restrict__ Wb, int wc0, int wc1, int wc2, int wjoff,
    const float* __restrict__ biasb,
    const f16* __restrict__ srcz, long src_zs,
    f16* __restrict__ outz, long out_zs, int Tout) {
  constexpr int PADL = (K == 5) ? 3 : 0;
  constexpr int TWIN = 32 + K - 1;
  constexpr int SLAB = K * 21 * 6144;
  constexpr int NS = 21 * K;
  __shared__ __align__(16) f16 sXs[2][4][40][24];  // dbuf [batch][t-window][ci pad 48B]
  __shared__ __align__(16) f16 sWs[3][6144];       // 3-buffer lane-ordered W
  int z = blockIdx.z;
  int nnode = z >> 1, j = z & 1;
  int blk = wc0 + wc1 * nnode + wc2 * (nnode >> 1);
  int slot = nnode * 4 + wjoff + j;
  const uint4* inq = (const uint4*)(inz + (size_t)z * in_zs);
  const uint32_t* wsl = (const uint32_t*)(Wb + (size_t)slot * SLAB);
  const float* bias = biasb + (size_t)(blk * 4 + wjoff + j) * Mn;
  int b0 = blockIdx.x * 4;
  int t0 = blockIdx.y * 32;
  int tid = threadIdx.x;
  int lane = tid & 63;
  int wv = tid >> 6;
  int wm = wv & 3, wc = wv >> 2;

  f32x16 acc[6];
#pragma unroll
  for (int i = 0; i < 6; ++i)
#pragma unroll
    for (int q = 0; q < 16; ++q) acc[i][q] = 0.f;

  auto stageX = [&](int cib, int xb) {
    uint32_t* dXu = (uint32_t*)&sXs[xb][0][0][0];
    constexpr int NX4 = 4 * TWIN * 2;
    for (int idx = tid; idx < NX4; idx += 512) {
      int u2 = idx & 1;
      int rr = idx >> 1;
      int tt = rr % TWIN;
      int bl = rr / TWIN;
      int ts = t0 + tt - PADL;
      ts = max(0, min(ts, Tin - 1));
      uint4 v = inq[((((size_t)(b0 + bl)) * Tin + ts) * Mp + cib * 16) / 8 + u2];
      *(uint4*)&dXu[(bl * 40 + tt) * 12 + u2 * 4] = v;
    }
  };
  auto stageW = [&](int s, int buf) {
    int cib = s / K, k = s - cib * K;
    const uint32_t* wp = wsl + ((size_t)(k * 21 + cib)) * 3072;
    uint32_t* dst = (uint32_t*)&sWs[buf][0];
    for (int i = tid; i < 768; i += 512) gll16(wp + i * 4, dst + i * 4);
  };

  stageX(0, 0);
  stageW(0, 0);
  stageW(1, 1);
  __syncthreads();
  int xb = 0;
#pragma unroll 1
  for (int s = 0; s < NS; ++s) {
    int cib = s / K, k = s - cib * K;
    __builtin_amdgcn_s_barrier();
    asm volatile("" ::: "memory");
    f16x8 ah = *(const f16x8*)&sXs[xb][wm][(lane & 31) + k][(lane >> 5) * 8];
    const f16* sw = &sWs[s % 3][0];
#pragma unroll
    for (int ct = 0; ct < 6; ++ct) {
      f16x8 bw = *(const f16x8*)&sw[((wc * 6 + ct) * 256 + (lane >> 5) * 128 + (lane & 31) * 4) * 2];
      acc[ct] = __builtin_amdgcn_mfma_f32_32x32x16_f16(ah, bw, acc[ct], 0, 0, 0);
    }
    if (k == K - 1 && cib + 1 < 21) stageX(cib + 1, xb ^ 1);
    if (s + 2 < NS) stageW(s + 2, (s + 2) % 3);
    asm volatile("s_waitcnt lgkmcnt(0)" ::: "memory");
    if (s + 2 < NS) {
      if (wv < 4) asm volatile("s_waitcnt vmcnt(2)" ::: "memory");
      else        asm volatile("s_waitcnt vmcnt(1)" ::: "memory");
    } else {
      asm volatile("s_waitcnt vmcnt(0)" ::: "memory");
    }
    if (k == K - 1) xb ^= 1;
  }
  // epilogue
  f16* o = outz + (size_t)z * out_zs;
  const f16* s = srcz ? srcz + (size_t)(z ^ 1) * src_zs : nullptr;
#pragma unroll
  for (int ct = 0; ct < 6; ++ct) {
    int co = wc * 192 + ct * 32 + (lane & 31);
    if (co >= Mp) continue;
    float bb = (co < Mn) ? bias[co] : 0.f;
#pragma unroll
    for (int r = 0; r < 16; ++r) {
      int row = (r & 3) + 8 * (r >> 2) + 4 * (lane >> 5);
      int t = t0 + row;
      if (t >= Tout) continue;
      size_t oo = (((size_t)(b0 + wm)) * Tout + t) * Mp + co;
      float res;
      if (co >= Mn) {
        res = 0.f;
      } else {
        float v = acc[ct][r] + bb;
        if constexpr (MK == 0) {
          res = v > 0.f ? v : 0.01f * v;
        } else {
          float sv = (float)s[oo];
          float th = tanh_f(v);
          if constexpr (MK == 1) res = sv * __expf(th);
          else res = (j == 0) ? sv + th : sv - th;
        }
      }
      o[oo] = (f16)res;
    }
  }
}

// ================= final combine: XR = x + interleave(leaves); + fp16 copy ===
__global__ __launch_bounds__(256) void combine_k(const float* __restrict__ x, const f16* __restrict__ lv,
                                                 float* __restrict__ XR, f16* __restrict__ XRh) {
  int b = blockIdx.x, p = blockIdx.y;
  int c = ((p & 1) << 2) | (p & 2) | ((p >> 2) & 1);
  int row = p >> 3;
  size_t li = (((size_t)c * Bn + b) * 24 + row) * Mp;
  size_t xi = ((size_t)b * Pn + p) * Mn;
  size_t hi = ((size_t)b * Pn + p) * Mp;
  for (int m = threadIdx.x; m < Mp; m += 256) {
    if (m < Mn) {
      float v = x[xi + m] + (float)lv[li + m];
      XR[xi + m] = v;
      XRh[hi + m] = (f16)v;
    } else {
      XRh[hi + m] = (f16)0.f;
    }
  }
}

// ================= conv2d via MFMA (2-phase): XRh -> Cch (L,B,HIDC f16) =====
// block: 32 batches x 4 output rows (1 per wave) x 128 co. 126 ksteps.
__global__ __launch_bounds__(256, 4) void conv2d_mfma(
    const f16* __restrict__ xh, const f16* __restrict__ Wh,
    const float* __restrict__ bias, f16* __restrict__ out) {
  __shared__ __align__(16) f16 sXs[2][9][32][24];  // dbuf [t-window][batch][ci pad]
  __shared__ __align__(16) f16 sWs[2][2048];       // dbuf lane-ordered W
  int b0 = blockIdx.x * 32;
  int l0 = blockIdx.y * 4;
  int tid = threadIdx.x;
  int lane = tid & 63;
  int wv = tid >> 6;  // wave = output-row offset 0..3

  f32x16 acc[4];
#pragma unroll
  for (int i = 0; i < 4; ++i)
#pragma unroll
    for (int q = 0; q < 16; ++q) acc[i][q] = 0.f;

  const uint4* xq = (const uint4*)xh;

  auto stageX = [&](int cib, int xb) {
    uint32_t* dXu = (uint32_t*)&sXs[xb][0][0][0];
    for (int idx = tid; idx < 576; idx += 256) {
      int u = idx & 1;
      int rr = idx >> 1;
      int bb = rr & 31, tt = rr >> 5;
      int p = min(l0 + tt, Pn - 1);
      uint4 v = xq[((((size_t)(b0 + bb)) * Pn + p) * Mp + cib * 16) / 8 + u];
      *(uint4*)&dXu[(tt * 32 + bb) * 12 + u * 4] = v;
    }
  };
  auto stageW = [&](int s, int wb) {
    int cib = s / CKn, k = s - cib * CKn;
    const uint32_t* wp = (const uint32_t*)(Wh + ((size_t)(k * 21 + cib)) * 2048);
    uint32_t* dst = (uint32_t*)&sWs[wb][0];
    gll16(wp + tid * 4, dst + tid * 4);  // 256 units, one per thread
  };

  stageX(0, 0);
  stageW(0, 0);
  __syncthreads();
  int wb = 0, xb = 0;
#pragma unroll 1
  for (int s = 0; s < 126; ++s) {
    int cib = s / CKn, k = s - cib * CKn;
    if (s + 1 < 126) stageW(s + 1, wb ^ 1);
    if (k == CKn - 1 && cib + 1 < 21) stageX(cib + 1, xb ^ 1);
    f16x8 ah = *(const f16x8*)&sXs[xb][wv + k][lane & 31][(lane >> 5) * 8];
    const f16* sw = &sWs[wb][0];
#pragma unroll
    for (int ct = 0; ct < 4; ++ct) {
      f16x8 bw = *(const f16x8*)&sw[(ct * 256 + (lane >> 5) * 128 + (lane & 31) * 4) * 2];
      acc[ct] = __builtin_amdgcn_mfma_f32_32x32x16_f16(ah, bw, acc[ct], 0, 0, 0);
    }
    __syncthreads();
    wb ^= 1;
    if (k == CKn - 1) xb ^= 1;
  }
  // epilogue: relu, f16, layout (l*Bn + b)*128 + co
  int l = l0 + wv;
  if (l < Ln) {
#pragma unroll
    for (int ct = 0; ct < 4; ++ct) {
      int co = ct * 32 + (lane & 31);
      float bb = bias[co];
#pragma unroll
      for (int r = 0; r < 16; ++r) {
        int brow = (r & 3) + 8 * (r >> 2) + 4 * (lane >> 5);
        float y = acc[ct][r] + bb;
        out[((size_t)l * Bn + (b0 + brow)) * HIDCn + co] = (f16)(y > 0.f ? y : 0.f);
      }
    }
  }
}

// ================= GRU1 input GEMM via MFMA =================
// A = Cch (47872 x 128 f16), W lane-ordered [k8][6144], out giA f32 (r,384)+bias
__global__ __launch_bounds__(512, 2) void gemm_gi(const f16* __restrict__ A, const f16* __restrict__ Wb,
                                                  const float* __restrict__ bias, float* __restrict__ out) {
  __shared__ __align__(16) f16 sA[128][136];  // 136-half row pad: 16B-aligned rows, 2-way banks
  __shared__ __align__(16) f16 sW[2][6144];
  int r0 = blockIdx.x * 128;
  int tid = threadIdx.x;
  int lane = tid & 63;
  int wv = tid >> 6;
  int wm = wv & 3, wc = wv >> 2;

  // stage A once: 128 rows x 128 halves = 128 x 16 uint4 = 2048 uint4
  const uint4* aq = (const uint4*)(A + (size_t)r0 * 128);
  for (int i = tid; i < 2048; i += 512) {
    int row = i >> 4, u = i & 15;
    *(uint4*)&sA[row][u * 8] = aq[i];
  }
  {
    const uint32_t* wp = (const uint32_t*)Wb;
    uint32_t* dst = (uint32_t*)&sW[0][0];
    for (int i = tid; i < 768; i += 512) gll16(wp + i * 4, dst + i * 4);
  }
  __syncthreads();

  f32x16 acc[6];
#pragma unroll
  for (int i = 0; i < 6; ++i)
#pragma unroll
    for (int q = 0; q < 16; ++q) acc[i][q] = 0.f;

  int wb = 0;
#pragma unroll 1
  for (int k = 0; k < 8; ++k) {
    if (k + 1 < 8) {
      const uint32_t* wp = (const uint32_t*)(Wb + (size_t)(k + 1) * 6144);
      uint32_t* dst = (uint32_t*)&sW[wb ^ 1][0];
      for (int i = tid; i < 768; i += 512) gll16(wp + i * 4, dst + i * 4);
    }
    f16x8 ah = *(const f16x8*)&sA[wm * 32 + (lane & 31)][k * 16 + (lane >> 5) * 8];
    const f16* sw = &sW[wb][0];
#pragma unroll
    for (int ct = 0; ct < 6; ++ct) {
      f16x8 bw = *(const f16x8*)&sw[((wc * 6 + ct) * 256 + (lane >> 5) * 128 + (lane & 31) * 4) * 2];
      acc[ct] = __builtin_amdgcn_mfma_f32_32x32x16_f16(ah, bw, acc[ct], 0, 0, 0);
    }
    __syncthreads();
    wb ^= 1;
  }
#pragma unroll
  for (int ct = 0; ct < 6; ++ct) {
    int c = wc * 192 + ct * 32 + (lane & 31);
    float bb = bias[c];
#pragma unroll
    for (int r = 0; r < 16; ++r) {
      int row = r0 + wm * 32 + (r & 3) + 8 * (r >> 2) + 4 * (lane >> 5);
      out[(size_t)row * 384 + c] = acc[ct][r] + bb;
    }
  }
}

// ================= GRU1 recurrent v5: per-wave columns, 1 raw barrier/step ===
// 8 waves x 16 cols; wave owns r,z,n gates for its cols. A = h broadcast ->
// every MFMA D-row equals the gate vector -> gates per-lane, no LDS round-trip.
// hp double-buffered; raw s_barrier (no vmcnt drain) + 2-step-deep gi prefetch.
__global__ __launch_bounds__(512) void gru1_k(const float* __restrict__ gi, const float* __restrict__ whh,
                                              const float* __restrict__ bhh, float* __restrict__ hout) {
  __shared__ __align__(16) uint32_t hp[2][64];  // h packed f16x2, double-buffered
  int n = blockIdx.x;
  int tid = threadIdx.x;
  int w = tid >> 6, l = tid & 63;
  int colg = l & 15, kg = l >> 4;
  int col = w * 16 + colg;

  // B-frags: wfr[gate][q] over whh row g = gate*128 + col, k = q*32+kg*8..+8
  f16x8 wfr[3][4];
#pragma unroll
  for (int g = 0; g < 3; ++g) {
    const float* wr = whh + (size_t)(g * 128 + col) * 128;
#pragma unroll
    for (int q = 0; q < 4; ++q) {
      const float4* s4 = (const float4*)(wr + q * 32 + kg * 8);
      float4 lo = s4[0], hi = s4[1];
      f16x8 f;
      f[0] = (f16)lo.x; f[1] = (f16)lo.y; f[2] = (f16)lo.z; f[3] = (f16)lo.w;
      f[4] = (f16)hi.x; f[5] = (f16)hi.y; f[6] = (f16)hi.z; f[7] = (f16)hi.w;
      wfr[g][q] = f;
    }
  }
  float bh_r = bhh[col], bh_z = bhh[128 + col], bh_n = bhh[256 + col];
  if (tid < 128) ((uint32_t*)hp)[tid] = 0u;
  float hprev = 0.f;
  // 2-deep gi prefetch slots
  float gA0, gA1, gA2, gB0, gB1, gB2;
  {
    const float* gp = gi + (size_t)n * 384;
    gA0 = gp[col]; gA1 = gp[128 + col]; gA2 = gp[256 + col];
    const float* gq = gi + ((size_t)Bn + n) * 384;
    gB0 = gq[col]; gB1 = gq[128 + col]; gB2 = gq[256 + col];
  }
  __syncthreads();

  auto gstep = [&](int T, float& G0, float& G1, float& G2, int RB) {
    float u0 = G0, u1 = G1, u2 = G2;
    if (T + 2 < Ln) {
      const float* gp = gi + ((size_t)(T + 2) * Bn + n) * 384;
      G0 = gp[col]; G1 = gp[128 + col]; G2 = gp[256 + col];
    }
    f32x4 ac0{}, ac1{}, ac2{};
#pragma unroll
    for (int q = 0; q < 4; ++q) {
      f16x8 af = __builtin_bit_cast(f16x8, *(const uint4*)&hp[RB][q * 16 + kg * 4]);
      ac0 = __builtin_amdgcn_mfma_f32_16x16x32_f16(af, wfr[0][q], ac0, 0, 0, 0);
      ac1 = __builtin_amdgcn_mfma_f32_16x16x32_f16(af, wfr[1][q], ac1, 0, 0, 0);
      ac2 = __builtin_amdgcn_mfma_f32_16x16x32_f16(af, wfr[2][q], ac2, 0, 0, 0);
    }
    float rg = sigmf(u0 + bh_r + ac0[0]);
    float zg = sigmf(u1 + bh_z + ac1[0]);
    float ng = tanh_f(u2 + bh_n + rg * ac2[0]);
    float hnew = (1.f - zg) * ng + zg * hprev;
    hprev = hnew;
    float other = __shfl_xor(hnew, 1, 64);
    if (l < 16 && !(l & 1)) {
      f16 a = (f16)hnew, b2 = (f16)other;
      hp[RB ^ 1][w * 8 + (l >> 1)] = (uint32_t)__builtin_bit_cast(unsigned short, a) |
                                     ((uint32_t)__builtin_bit_cast(unsigned short, b2) << 16);
    }
    asm volatile("s_waitcnt lgkmcnt(0)" ::: "memory");
    __builtin_amdgcn_s_barrier();
    asm volatile("" ::: "memory");
  };

#pragma unroll 1
  for (int t = 0; t + 1 < Ln; t += 2) {
    gstep(t, gA0, gA1, gA2, 0);
    gstep(t + 1, gB0, gB1, gB2, 1);
  }
  gstep(Ln - 1, gA0, gA1, gA2, 0);  // Ln odd: final step reads hp[0]
  if (l < 16) hout[(size_t)n * 128 + col] = hprev;
}

// ================= skip-GRU input gemm (f16 Cc) =================
__global__ __launch_bounds__(256) void gis_k(const f16* __restrict__ cc, const float* __restrict__ wih,
                                             const float* __restrict__ bih, float* __restrict__ gi) {
  __shared__ float sx[24 * 128];
  int t = blockIdx.x, b = blockIdx.y;
  int tid = threadIdx.x;
  for (int idx = tid; idx < 24 * 128; idx += 256) {
    int sk = idx >> 7, i = idx & 127;
    int l = 19 + t * 24 + sk;
    sx[idx] = (float)cc[((size_t)l * Bn + b) * HIDCn + i];
  }
  __syncthreads();
  for (int idx = tid; idx < 576; idx += 256) {
    int sk = idx / 24, g = idx - sk * 24;
    float a = bih[g];
    for (int i = 0; i < 128; ++i) a = fmaf(sx[sk * 128 + i], wih[g * 128 + i], a);
    gi[((size_t)t * (Bn * SKIPn) + b * 24 + sk) * 24 + g] = a;
  }
}

// ================= skip-GRU recurrent =================
__global__ __launch_bounds__(256) void grus_k(const float* __restrict__ gi, const float* __restrict__ whh,
                                              const float* __restrict__ bhh, float* __restrict__ hout) {
  __shared__ float sw[24 * 8];
  __shared__ float sb[24];
  int tid = threadIdx.x;
  int n = blockIdx.x * 256 + tid;
  if (tid < 192) sw[tid] = whh[tid];
  if (tid < 24) sb[tid] = bhh[tid];
  __syncthreads();
  float h[8];
#pragma unroll
  for (int jj = 0; jj < 8; ++jj) h[jj] = 0.f;
  for (int t = 0; t < PTn; ++t) {
    const float* gir = gi + ((size_t)t * (Bn * SKIPn) + n) * 24;
    float gh[24];
#pragma unroll
    for (int g = 0; g < 24; ++g) {
      float a = sb[g];
#pragma unroll
      for (int jj = 0; jj < 8; ++jj) a = fmaf(sw[g * 8 + jj], h[jj], a);
      gh[g] = a;
    }
#pragma unroll
    for (int jj = 0; jj < 8; ++jj) {
      float rg = sigmf(gir[jj] + gh[jj]);
      float zg = sigmf(gir[8 + jj] + gh[8 + jj]);
      float ng = tanh_f(gir[16 + jj] + rg * gh[16 + jj]);
      h[jj] = (1.f - zg) * ng + zg * h[jj];
    }
  }
#pragma unroll
  for (int jj = 0; jj < 8; ++jj) hout[(size_t)n * 8 + jj] = h[jj];
}

// ================= final linear + highway =================
__global__ __launch_bounds__(384) void final_k(const float* __restrict__ h1, const float* __restrict__ hsb,
                                               const float* __restrict__ lw, const float* __restrict__ lb,
                                               const float* __restrict__ xr, const float* __restrict__ hww,
                                               const float* __restrict__ hwb, float* __restrict__ out) {
  __shared__ float sr[320];
  __shared__ float shw[24];
  int b = blockIdx.x;
  int tid = threadIdx.x;
  if (tid < 128) sr[tid] = h1[(size_t)b * 128 + tid];
  else if (tid < 320) sr[tid] = hsb[(size_t)b * 192 + (tid - 128)];
  if (tid >= 320 && tid < 344) shw[tid - 320] = hww[tid - 320];
  __syncthreads();
  int m = tid;
  if (m >= Mn) return;
  float a = lb[m];
  const float* wr = lw + (size_t)m * 320;
  for (int c = 0; c < 320; ++c) a = fmaf(sr[c], wr[c], a);
  float z = hwb[0];
  const float* xrr = xr + ((size_t)b * Pn + (Pn - HWn)) * Mn + m;
#pragma unroll
  for (int k = 0; k < HWn; ++k) z = fmaf(xrr[(size_t)k * Mn], shw[k], z);
  out[(size_t)b * Mn + m] = a + z;
}

extern "C" void kernel_launch(void* const* d_in, const int* in_sizes, int n_in,
                              void* d_out, int out_size, void* d_ws, size_t ws_size,
                              hipStream_t stream) {
  const float* x = (const float*)d_in[0];
  const float* tw1 = (const float*)d_in[1];
  const float* tb1 = (const float*)d_in[2];
  const float* tw2 = (const float*)d_in[3];
  const float* tb2 = (const float*)d_in[4];
  const float* c1w = (const float*)d_in[5];
  const float* c1b = (const float*)d_in[6];
  const float* g1wih = (const float*)d_in[7];
  const float* g1whh = (const float*)d_in[8];
  const float* g1bih = (const float*)d_in[9];
  const float* g1bhh = (const float*)d_in[10];
  const float* gswih = (const float*)d_in[11];
  const float* gswhh = (const float*)d_in[12];
  const float* gsbih = (const float*)d_in[13];
  const float* gsbhh = (const float*)d_in[14];
  const float* l1w = (const float*)d_in[15];
  const float* l1b = (const float*)d_in[16];
  const float* hww = (const float*)d_in[17];
  const float* hwb = (const float*)d_in[18];
  float* out = (float*)d_out;

  // ---------- workspace plan (~214 MB) ----------
  const size_t Ah = 17891328ull, Bh = 17891328ull, Ch = 17203200ull;  // halves per plane
  f16* Aq = (f16*)d_ws;
  f16* Bq = Aq + Ah;
  f16* Cq = Bq + Bh;
  f16* Wl1 = Cq + Ch;                      // 16*5*21*6144 = 10,321,920 halves
  f16* Wl2 = Wl1 + 10321920ull;            // 16*3*21*6144 = 6,193,152 halves
  f16* Wc2 = (f16*)(Wl2 + 6193152ull);     // conv2d f16 weight slab (258,048 halves)
  f16* Wgi = Wc2 + 258048ull;              // gru1 wih f16 slab (49,152 halves; fits pre-giA gap)
  float* giA = (float*)(Wl2 + 6193152ull) + 246528ull;  // 18,382,848 floats (offset as before)
  float* h1 = giA + 18382848ull;
  float* hsb = h1 + (size_t)Bn * HIDRn;
  float* gis = hsb + (size_t)Bn * SKIPn * HIDSn;
  // post-tree aliases
  float* XR = (float*)Bq;                  // 63.1 MB spanning B + part of C
  f16* Cch = Aq;                           // 12.25 MB f16 conv2d output in A
  f16* XRh = Wl1;                          // fp16 XR, B*P*Mp = 16,515,072 halves == Wl1+Wl2

  // region schedule (validated round 3): per level {EO, S1, CD, S3, EU}
  f16* EO[3] = {Aq, Aq, Bq};
  f16* S1[3] = {Bq, Cq, Aq};
  f16* CD[3] = {Cq, Bq, Cq};
  f16* S3[3] = {Aq, Aq, Bq};
  f16* EU[3] = {Bq, Cq, Aq};
  const int WC0[3] = {0, 1, 2}, WC1[3] = {0, 3, 1}, WC2[3] = {0, 0, 1};

  repack_c2w<<<dim3(1008), 256, 0, stream>>>(c1w, Wc2);
  repack_giw<<<dim3(192), 256, 0, stream>>>(g1wih, Wgi);

  for (int L = 0; L < 3; ++L) {
    int NL = 1 << L;
    int Th = 96 >> L;
    int Z = 2 * NL;
    long zsEO = (long)Bn * Th * Mp;
    long zsS1 = (long)Bn * (Th + 2) * Mp;
    repack_w<<<dim3(24, 5 * 21, NL * 4), 256, 0, stream>>>(tw1, Wl1, 5, WC0[L], WC1[L], WC2[L]);
    repack_w<<<dim3(24, 3 * 21, NL * 4), 256, 0, stream>>>(tw2, Wl2, 3, WC0[L], WC1[L], WC2[L]);
    if (L == 0)
      deint_k<<<dim3(Bn, Th, 2), 256, 0, stream>>>(x, nullptr, 0, EO[0], Th);
    else
      deint_k<<<dim3(Bn, Th, Z), 256, 0, stream>>>(nullptr, EU[L - 1], 2 * Th, EO[L], Th);
    int ty1 = (Th + 2 + 31) / 32, ty2 = (Th + 31) / 32;
    conv_mfma<5, 0><<<dim3(64, ty1, Z), 512, 0, stream>>>(
        EO[L], zsEO, Th, Wl1, WC0[L], WC1[L], WC2[L], 0, tb1,
        nullptr, 0, S1[L], zsS1, Th + 2);
    conv_mfma<3, 1><<<dim3(64, ty2, Z), 512, 0, stream>>>(
        S1[L], zsS1, Th + 2, Wl2, WC0[L], WC1[L], WC2[L], 0, tb2,
        EO[L], zsEO, CD[L], zsEO, Th);
    conv_mfma<5, 0><<<dim3(64, ty1, Z), 512, 0, stream>>>(
        CD[L], zsEO, Th, Wl1, WC0[L], WC1[L], WC2[L], 2, tb1,
        nullptr, 0, S3[L], zsS1, Th + 2);
    conv_mfma<3, 2><<<dim3(64, ty2, Z), 512, 0, stream>>>(
        S3[L], zsS1, Th + 2, Wl2, WC0[L], WC1[L], WC2[L], 2, tb2,
        CD[L], zsEO, EU[L], zsEO, Th);
  }

  combine_k<<<dim3(Bn, Pn), 256, 0, stream>>>(x, EU[2], XR, XRh);

  conv2d_mfma<<<dim3(Bn / 32, (Ln + 3) / 4), 256, 0, stream>>>(XRh, Wc2, c1b, Cch);
  gemm_gi<<<dim3((Ln * Bn) / 128), 512, 0, stream>>>(Cch, Wgi, g1bih, giA);
  gru1_k<<<dim3(Bn), 512, 0, stream>>>(giA, g1whh, g1bhh, h1);
  gis_k<<<dim3(PTn, Bn), 256, 0, stream>>>(Cch, gswih, gsbih, gis);
  grus_k<<<dim3((Bn * SKIPn) / 256), 256, 0, stream>>>(gis, gswhh, gsbhh, hsb);
  final_k<<<dim3(Bn), 384, 0, stream>>>(h1, hsb, l1w, l1b, XR, hww, hwb, out);
}

// Round 12
// 1688.023 us; speedup vs baseline: 1.1064x; 1.0372x over previous
//
#include <hip/hip_runtime.h>
#include <cstddef>
#include <cstdint>

#define Bn 256
#define Pn 192
#define Mn 321
#define Mp 336     // padded channel dim (multiple of 16)
#define HIDCn 128
#define HIDRn 128
#define HIDSn 8
#define CKn 6
#define SKIPn 24
#define HWn 24
#define Ln 187   // Pn - CKn + 1
#define PTn 7

typedef _Float16 f16;
typedef f16 f16x2 __attribute__((ext_vector_type(2)));
typedef f16 f16x8 __attribute__((ext_vector_type(8)));
typedef float f32x4 __attribute__((ext_vector_type(4)));
typedef float f32x16 __attribute__((ext_vector_type(16)));

__device__ __forceinline__ float rcpf(float x) {
#if defined(__has_builtin) && __has_builtin(__builtin_amdgcn_rcpf)
  return __builtin_amdgcn_rcpf(x);
#else
  return 1.f / x;
#endif
}
// fast sigmoid/tanh via v_exp_f32 + v_rcp_f32 (saturate correctly at +/-inf)
__device__ __forceinline__ float sigmf(float x) { return rcpf(1.f + __expf(-x)); }
__device__ __forceinline__ float tanh_f(float x) {
  float t = __expf(2.f * x);
  return 1.f - 2.f * rcpf(t + 1.f);
}

// async global->LDS 16B copy; dest must be wave-uniform-base + lane*size pattern
__device__ __forceinline__ void gll16(const void* g, void* l) {
#if defined(__has_builtin) && __has_builtin(__builtin_amdgcn_global_load_lds)
  __builtin_amdgcn_global_load_lds((const __attribute__((address_space(1))) void*)g,
                                   (__attribute__((address_space(3))) void*)l, 16, 0, 0);
#else
  *(uint4*)l = *(const uint4*)g;
#endif
}

// lane-ordered position of (co, cc) inside a [coN x 16] f16 tile:
// ct-tile = co>>5 (256 dwords each), lane = (cc>>3)*32 + (co&31), dword (cc>>1)&3.
__device__ __forceinline__ int lanepos(int co, int cc) {
  int ctg = co >> 5, row = co & 31;
  int h = (cc >> 3) & 1, d = (cc >> 1) & 3;
  return ((ctg * 256 + h * 128 + row * 4 + d) << 1) | (cc & 1);
}

// ================= tree weight repack + fp16 cast (lane-ordered) ============
__global__ __launch_bounds__(256) void repack_w(const float* __restrict__ w, f16* __restrict__ out,
                                                int K, int c0, int c1, int c2) {
  int s = blockIdx.z;
  int n = s >> 2, jj = s & 3;
  int blk = c0 + c1 * n + c2 * (n >> 1);
  int kcib = blockIdx.y;
  int k = kcib / 21, cib = kcib - 21 * k;
  int idx = blockIdx.x * 256 + threadIdx.x;  // [0, 6144) source = co*16+cc
  int co = idx >> 4, cc = idx & 15;
  int ci = cib * 16 + cc;
  f16 val = (f16)0.f;
  if (co < Mn && ci < Mn)
    val = (f16)w[(((size_t)(blk * 4 + jj) * Mn + co) * Mn + ci) * K + k];
  out[(((size_t)s * K + k) * 21 + cib) * 6144 + lanepos(co, cc)] = val;
}

// ================= conv2d weight repack -> f16 slab (lane-ordered) ==========
__global__ __launch_bounds__(256) void repack_c2w(const float* __restrict__ w, f16* __restrict__ out) {
  int idx = blockIdx.x * 256 + threadIdx.x;  // [0, 258048)
  int cc = idx & 15;
  int co = (idx >> 4) & 127;
  int kcib = idx >> 11;  // 0..125
  int k = kcib / 21, cib = kcib - 21 * k;
  int m = cib * 16 + cc;
  f16 v = (f16)0.f;
  if (m < Mn) v = (f16)w[((size_t)co * CKn + k) * Mn + m];
  out[((size_t)(k * 21 + cib)) * 2048 + lanepos(co, cc)] = v;
}

// ================= gru1 input-weight repack -> f16 slab (lane-ordered) ======
__global__ __launch_bounds__(256) void repack_giw(const float* __restrict__ w, f16* __restrict__ out) {
  int idx = blockIdx.x * 256 + threadIdx.x;  // [0, 49152)
  int cc = idx & 15;
  int co = (idx >> 4) % 384;
  int k = idx / (16 * 384);  // 0..7
  out[(size_t)k * 6144 + lanepos(co, cc)] = (f16)w[(size_t)co * 128 + k * 16 + cc];
}

// ================= deinterleave x -> e/o planes (level 0 only) ==============
__global__ __launch_bounds__(256) void deint_k(const float* __restrict__ x32,
                                               f16* __restrict__ o, int Th) {
  int b = blockIdx.x, t = blockIdx.y, z = blockIdx.z;
  int eo = z & 1;
  int srow = 2 * t + eo;
  size_t ooff = (((size_t)z * Bn + b) * Th + t) * Mp;
  const float* xp = x32 + ((size_t)b * Pn + srow) * Mn;
  for (int m = threadIdx.x; m < Mp; m += 256)
    o[ooff + m] = (m < Mn) ? (f16)xp[m] : (f16)0.f;
}

// ================= MFMA branch conv (r9-proven 2-phase pipelined fp16) ======
// m-tile 128 = 4 batch x 32 t; co 384 over 2 wave-halves; 512 thr / 8 waves.
// wave shape: 1 A-frag + 6 B-frags -> acc[6]. W dbuf staged 1 step ahead via
// global_load_lds; X dbuf per-cib; one __syncthreads per k-step.
// MK 0: leaky   MK 1: out = src*exp(tanh(v))   MK 2: out = src +/- tanh(v)
// dmode (MK2 only): 1 = write deinterleaved child planes (fused deint).
template <int K, int MK>
__global__ __launch_bounds__(512, 2) void conv_mfma(
    const f16* __restrict__ inz, long in_zs, int Tin,
    const f16* __restrict__ Wb, int wc0, int wc1, int wc2, int wjoff,
    const float* __restrict__ biasb,
    const f16* __restrict__ srcz, long src_zs,
    f16* __restrict__ outz, long out_zs, int Tout, int dmode) {
  constexpr int PADL = (K == 5) ? 3 : 0;
  constexpr int TWIN = 32 + K - 1;
  constexpr int SLAB = K * 21 * 6144;
  constexpr int NS = 21 * K;
  __shared__ __align__(16) f16 sXs[2][4][40][24];  // dbuf [batch][t-window][ci pad 48B]
  __shared__ __align__(16) f16 sWs[2][6144];       // dbuf lane-ordered W
  int z = blockIdx.z;
  int nnode = z >> 1, j = z & 1;
  int blk = wc0 + wc1 * nnode + wc2 * (nnode >> 1);
  int slot = nnode * 4 + wjoff + j;
  const uint4* inq = (const uint4*)(inz + (size_t)z * in_zs);
  const uint32_t* wsl = (const uint32_t*)(Wb + (size_t)slot * SLAB);
  const float* bias = biasb + (size_t)(blk * 4 + wjoff + j) * Mn;
  int b0 = blockIdx.x * 4;
  int t0 = blockIdx.y * 32;
  int tid = threadIdx.x;
  int lane = tid & 63;
  int wv = tid >> 6;
  int wm = wv & 3, wc = wv >> 2;

  f32x16 acc[6];
#pragma unroll
  for (int i = 0; i < 6; ++i)
#pragma unroll
    for (int q = 0; q < 16; ++q) acc[i][q] = 0.f;

  auto stageX = [&](int cib, int xb) {
    uint32_t* dXu = (uint32_t*)&sXs[xb][0][0][0];
    constexpr int NX4 = 4 * TWIN * 2;
    for (int idx = tid; idx < NX4; idx += 512) {
      int u2 = idx & 1;
      int rr = idx >> 1;
      int tt = rr % TWIN;
      int bl = rr / TWIN;
      int ts = t0 + tt - PADL;
      ts = max(0, min(ts, Tin - 1));
      uint4 v = inq[((((size_t)(b0 + bl)) * Tin + ts) * Mp + cib * 16) / 8 + u2];
      *(uint4*)&dXu[(bl * 40 + tt) * 12 + u2 * 4] = v;
    }
  };
  auto stageW = [&](int s, int wb) {
    int cib = s / K, k = s - cib * K;
    const uint32_t* wp = wsl + ((size_t)(k * 21 + cib)) * 3072;
    uint32_t* dst = (uint32_t*)&sWs[wb][0];
    for (int i = tid; i < 768; i += 512) gll16(wp + i * 4, dst + i * 4);
  };

  stageX(0, 0);
  stageW(0, 0);
  __syncthreads();
  int wb = 0, xb = 0;
#pragma unroll 1
  for (int s = 0; s < NS; ++s) {
    int cib = s / K, k = s - cib * K;
    if (s + 1 < NS) stageW(s + 1, wb ^ 1);
    if (k == K - 1 && cib + 1 < 21) stageX(cib + 1, xb ^ 1);
    f16x8 ah = *(const f16x8*)&sXs[xb][wm][(lane & 31) + k][(lane >> 5) * 8];
    const f16* sw = &sWs[wb][0];
#pragma unroll
    for (int ct = 0; ct < 6; ++ct) {
      f16x8 bw = *(const f16x8*)&sw[((wc * 6 + ct) * 256 + (lane >> 5) * 128 + (lane & 31) * 4) * 2];
      acc[ct] = __builtin_amdgcn_mfma_f32_32x32x16_f16(ah, bw, acc[ct], 0, 0, 0);
    }
    __syncthreads();
    wb ^= 1;
    if (k == K - 1) xb ^= 1;
  }
  // epilogue
  f16* o = outz + (dmode ? (size_t)0 : (size_t)z * out_zs);
  const f16* s = srcz ? srcz + (size_t)(z ^ 1) * src_zs : nullptr;
#pragma unroll
  for (int ct = 0; ct < 6; ++ct) {
    int co = wc * 192 + ct * 32 + (lane & 31);
    if (co >= Mp) continue;
    float bb = (co < Mn) ? bias[co] : 0.f;
#pragma unroll
    for (int r = 0; r < 16; ++r) {
      int row = (r & 3) + 8 * (r >> 2) + 4 * (lane >> 5);
      int t = t0 + row;
      if (t >= Tout) continue;
      size_t osrc = (((size_t)(b0 + wm)) * Tout + t) * Mp + co;
      float res;
      if (co >= Mn) {
        res = 0.f;
      } else {
        float v = acc[ct][r] + bb;
        if constexpr (MK == 0) {
          res = v > 0.f ? v : 0.01f * v;
        } else {
          float sv = (float)s[osrc];
          float th = tanh_f(v);
          if constexpr (MK == 1) res = sv * __expf(th);
          else res = (j == 0) ? sv + th : sv - th;
        }
      }
      size_t odst = osrc;
      if constexpr (MK == 2) {
        if (dmode)
          odst = (((size_t)(2 * z + (t & 1)) * Bn + (b0 + wm)) * (Tout >> 1) + (t >> 1)) * Mp + co;
      }
      o[odst] = (f16)res;
    }
  }
}

// ================= final combine: XR = x + interleave(leaves); + fp16 copy ===
__global__ __launch_bounds__(256) void combine_k(const float* __restrict__ x, const f16* __restrict__ lv,
                                                 float* __restrict__ XR, f16* __restrict__ XRh) {
  int b = blockIdx.x, p = blockIdx.y;
  int c = ((p & 1) << 2) | (p & 2) | ((p >> 2) & 1);
  int row = p >> 3;
  size_t li = (((size_t)c * Bn + b) * 24 + row) * Mp;
  size_t xi = ((size_t)b * Pn + p) * Mn;
  size_t hi = ((size_t)b * Pn + p) * Mp;
  for (int m = threadIdx.x; m < Mp; m += 256) {
    if (m < Mn) {
      float v = x[xi + m] + (float)lv[li + m];
      XR[xi + m] = v;
      XRh[hi + m] = (f16)v;
    } else {
      XRh[hi + m] = (f16)0.f;
    }
  }
}

// ================= conv2d via MFMA (2-phase): XRh -> Cch (L,B,HIDC f16) =====
__global__ __launch_bounds__(256, 4) void conv2d_mfma(
    const f16* __restrict__ xh, const f16* __restrict__ Wh,
    const float* __restrict__ bias, f16* __restrict__ out) {
  __shared__ __align__(16) f16 sXs[2][9][32][24];  // dbuf [t-window][batch][ci pad]
  __shared__ __align__(16) f16 sWs[2][2048];       // dbuf lane-ordered W
  int b0 = blockIdx.x * 32;
  int l0 = blockIdx.y * 4;
  int tid = threadIdx.x;
  int lane = tid & 63;
  int wv = tid >> 6;  // wave = output-row offset 0..3

  f32x16 acc[4];
#pragma unroll
  for (int i = 0; i < 4; ++i)
#pragma unroll
    for (int q = 0; q < 16; ++q) acc[i][q] = 0.f;

  const uint4* xq = (const uint4*)xh;

  auto stageX = [&](int cib, int xb) {
    uint32_t* dXu = (uint32_t*)&sXs[xb][0][0][0];
    for (int idx = tid; idx < 576; idx += 256) {
      int u = idx & 1;
      int rr = idx >> 1;
      int bb = rr & 31, tt = rr >> 5;
      int p = min(l0 + tt, Pn - 1);
      uint4 v = xq[((((size_t)(b0 + bb)) * Pn + p) * Mp + cib * 16) / 8 + u];
      *(uint4*)&dXu[(tt * 32 + bb) * 12 + u * 4] = v;
    }
  };
  auto stageW = [&](int s, int wb) {
    int cib = s / CKn, k = s - cib * CKn;
    const uint32_t* wp = (const uint32_t*)(Wh + ((size_t)(k * 21 + cib)) * 2048);
    uint32_t* dst = (uint32_t*)&sWs[wb][0];
    gll16(wp + tid * 4, dst + tid * 4);  // 256 units, one per thread
  };

  stageX(0, 0);
  stageW(0, 0);
  __syncthreads();
  int wb = 0, xb = 0;
#pragma unroll 1
  for (int s = 0; s < 126; ++s) {
    int cib = s / CKn, k = s - cib * CKn;
    if (s + 1 < 126) stageW(s + 1, wb ^ 1);
    if (k == CKn - 1 && cib + 1 < 21) stageX(cib + 1, xb ^ 1);
    f16x8 ah = *(const f16x8*)&sXs[xb][wv + k][lane & 31][(lane >> 5) * 8];
    const f16* sw = &sWs[wb][0];
#pragma unroll
    for (int ct = 0; ct < 4; ++ct) {
      f16x8 bw = *(const f16x8*)&sw[(ct * 256 + (lane >> 5) * 128 + (lane & 31) * 4) * 2];
      acc[ct] = __builtin_amdgcn_mfma_f32_32x32x16_f16(ah, bw, acc[ct], 0, 0, 0);
    }
    __syncthreads();
    wb ^= 1;
    if (k == CKn - 1) xb ^= 1;
  }
  // epilogue: relu, f16, layout (l*Bn + b)*128 + co
  int l = l0 + wv;
  if (l < Ln) {
#pragma unroll
    for (int ct = 0; ct < 4; ++ct) {
      int co = ct * 32 + (lane & 31);
      float bb = bias[co];
#pragma unroll
      for (int r = 0; r < 16; ++r) {
        int brow = (r & 3) + 8 * (r >> 2) + 4 * (lane >> 5);
        float y = acc[ct][r] + bb;
        out[((size_t)l * Bn + (b0 + brow)) * HIDCn + co] = (f16)(y > 0.f ? y : 0.f);
      }
    }
  }
}

// ================= GRU1 input GEMM via MFMA =================
__global__ __launch_bounds__(512, 2) void gemm_gi(const f16* __restrict__ A, const f16* __restrict__ Wb,
                                                  const float* __restrict__ bias, float* __restrict__ out) {
  __shared__ __align__(16) f16 sA[128][136];  // 136-half row pad
  __shared__ __align__(16) f16 sW[2][6144];
  int r0 = blockIdx.x * 128;
  int tid = threadIdx.x;
  int lane = tid & 63;
  int wv = tid >> 6;
  int wm = wv & 3, wc = wv >> 2;

  // stage A once: 128 rows x 128 halves = 128 x 16 uint4 = 2048 uint4
  const uint4* aq = (const uint4*)(A + (size_t)r0 * 128);
  for (int i = tid; i < 2048; i += 512) {
    int row = i >> 4, u = i & 15;
    *(uint4*)&sA[row][u * 8] = aq[i];
  }
  {
    const uint32_t* wp = (const uint32_t*)Wb;
    uint32_t* dst = (uint32_t*)&sW[0][0];
    for (int i = tid; i < 768; i += 512) gll16(wp + i * 4, dst + i * 4);
  }
  __syncthreads();

  f32x16 acc[6];
#pragma unroll
  for (int i = 0; i < 6; ++i)
#pragma unroll
    for (int q = 0; q < 16; ++q) acc[i][q] = 0.f;

  int wb = 0;
#pragma unroll 1
  for (int k = 0; k < 8; ++k) {
    if (k + 1 < 8) {
      const uint32_t* wp = (const uint32_t*)(Wb + (size_t)(k + 1) * 6144);
      uint32_t* dst = (uint32_t*)&sW[wb ^ 1][0];
      for (int i = tid; i < 768; i += 512) gll16(wp + i * 4, dst + i * 4);
    }
    f16x8 ah = *(const f16x8*)&sA[wm * 32 + (lane & 31)][k * 16 + (lane >> 5) * 8];
    const f16* sw = &sW[wb][0];
#pragma unroll
    for (int ct = 0; ct < 6; ++ct) {
      f16x8 bw = *(const f16x8*)&sw[((wc * 6 + ct) * 256 + (lane >> 5) * 128 + (lane & 31) * 4) * 2];
      acc[ct] = __builtin_amdgcn_mfma_f32_32x32x16_f16(ah, bw, acc[ct], 0, 0, 0);
    }
    __syncthreads();
    wb ^= 1;
  }
#pragma unroll
  for (int ct = 0; ct < 6; ++ct) {
    int c = wc * 192 + ct * 32 + (lane & 31);
    float bb = bias[c];
#pragma unroll
    for (int r = 0; r < 16; ++r) {
      int row = r0 + wm * 32 + (r & 3) + 8 * (r >> 2) + 4 * (lane >> 5);
      out[(size_t)row * 384 + c] = acc[ct][r] + bb;
    }
  }
}

// ================= fused tail: gru1 + skip-gis + skip-grus + final ==========
// one block per batch, 512 threads. Phase A = proven gru1 v5; B/C/D in LDS.
__global__ __launch_bounds__(512) void tail_k(
    const float* __restrict__ gi, const float* __restrict__ whh, const float* __restrict__ bhh,
    const f16* __restrict__ cc, const float* __restrict__ swih, const float* __restrict__ sbih,
    const float* __restrict__ swhh, const float* __restrict__ sbhh,
    const float* __restrict__ lw, const float* __restrict__ lb,
    const float* __restrict__ xr, const float* __restrict__ hww, const float* __restrict__ hwb,
    float* __restrict__ out) {
  __shared__ __align__(16) uint32_t hp[2][64];  // h packed f16x2, double-buffered
  __shared__ float hfL[128];
  __shared__ float gisb[PTn][24][24];
  __shared__ float hsbL[192];
  __shared__ float ssw[192];
  __shared__ float ssb[24];
  __shared__ float shw[24];
  int n = blockIdx.x;
  int tid = threadIdx.x;
  int w = tid >> 6, l = tid & 63;
  int colg = l & 15, kg = l >> 4;
  int col = w * 16 + colg;

  // ---- Phase A: gru1 recurrent (r9-proven) ----
  f16x8 wfr[3][4];
#pragma unroll
  for (int g = 0; g < 3; ++g) {
    const float* wr = whh + (size_t)(g * 128 + col) * 128;
#pragma unroll
    for (int q = 0; q < 4; ++q) {
      const float4* s4 = (const float4*)(wr + q * 32 + kg * 8);
      float4 lo = s4[0], hi = s4[1];
      f16x8 f;
      f[0] = (f16)lo.x; f[1] = (f16)lo.y; f[2] = (f16)lo.z; f[3] = (f16)lo.w;
      f[4] = (f16)hi.x; f[5] = (f16)hi.y; f[6] = (f16)hi.z; f[7] = (f16)hi.w;
      wfr[g][q] = f;
    }
  }
  float bh_r = bhh[col], bh_z = bhh[128 + col], bh_n = bhh[256 + col];
  if (tid < 128) ((uint32_t*)hp)[tid] = 0u;
  if (tid >= 320 && tid < 344) shw[tid - 320] = hww[tid - 320];
  float hprev = 0.f;
  float gA0, gA1, gA2, gB0, gB1, gB2;
  {
    const float* gp = gi + (size_t)n * 384;
    gA0 = gp[col]; gA1 = gp[128 + col]; gA2 = gp[256 + col];
    const float* gq = gi + ((size_t)Bn + n) * 384;
    gB0 = gq[col]; gB1 = gq[128 + col]; gB2 = gq[256 + col];
  }
  __syncthreads();

  auto gstep = [&](int T, float& G0, float& G1, float& G2, int RB) {
    float u0 = G0, u1 = G1, u2 = G2;
    if (T + 2 < Ln) {
      const float* gp = gi + ((size_t)(T + 2) * Bn + n) * 384;
      G0 = gp[col]; G1 = gp[128 + col]; G2 = gp[256 + col];
    }
    f32x4 ac0{}, ac1{}, ac2{};
#pragma unroll
    for (int q = 0; q < 4; ++q) {
      f16x8 af = __builtin_bit_cast(f16x8, *(const uint4*)&hp[RB][q * 16 + kg * 4]);
      ac0 = __builtin_amdgcn_mfma_f32_16x16x32_f16(af, wfr[0][q], ac0, 0, 0, 0);
      ac1 = __builtin_amdgcn_mfma_f32_16x16x32_f16(af, wfr[1][q], ac1, 0, 0, 0);
      ac2 = __builtin_amdgcn_mfma_f32_16x16x32_f16(af, wfr[2][q], ac2, 0, 0, 0);
    }
    float rg = sigmf(u0 + bh_r + ac0[0]);
    float zg = sigmf(u1 + bh_z + ac1[0]);
    float ng = tanh_f(u2 + bh_n + rg * ac2[0]);
    float hnew = (1.f - zg) * ng + zg * hprev;
    hprev = hnew;
    float other = __shfl_xor(hnew, 1, 64);
    if (l < 16 && !(l & 1)) {
      f16 a = (f16)hnew, b2 = (f16)other;
      hp[RB ^ 1][w * 8 + (l >> 1)] = (uint32_t)__builtin_bit_cast(unsigned short, a) |
                                     ((uint32_t)__builtin_bit_cast(unsigned short, b2) << 16);
    }
    asm volatile("s_waitcnt lgkmcnt(0)" ::: "memory");
    __builtin_amdgcn_s_barrier();
    asm volatile("" ::: "memory");
  };

#pragma unroll 1
  for (int t = 0; t + 1 < Ln; t += 2) {
    gstep(t, gA0, gA1, gA2, 0);
    gstep(t + 1, gB0, gB1, gB2, 1);
  }
  gstep(Ln - 1, gA0, gA1, gA2, 0);
  if (l < 16) hfL[col] = hprev;
  __syncthreads();

  // ---- Phase B: skip-GRU input gemm into LDS ----
  for (int idx = tid; idx < PTn * 576; idx += 512) {
    int t = idx / 576, r2 = idx - t * 576;
    int sk = r2 / 24, g = r2 - sk * 24;
    const f16* cr = cc + ((size_t)(19 + t * 24 + sk) * Bn + n) * HIDCn;
    const float* wr = swih + (size_t)g * 128;
    float a = sbih[g];
#pragma unroll 4
    for (int i8 = 0; i8 < 16; ++i8) {
      f16x8 c8 = *(const f16x8*)(cr + i8 * 8);
#pragma unroll
      for (int u = 0; u < 8; ++u) a = fmaf((float)c8[u], wr[i8 * 8 + u], a);
    }
    gisb[t][sk][g] = a;
  }
  if (tid < 192) ssw[tid] = swhh[tid];
  if (tid < 24) ssb[tid] = sbhh[tid];
  __syncthreads();

  // ---- Phase C: skip-GRU recurrent (24 lanes) ----
  if (tid < 24) {
    int sk = tid;
    float h[8];
#pragma unroll
    for (int jj = 0; jj < 8; ++jj) h[jj] = 0.f;
    for (int t = 0; t < PTn; ++t) {
      float gh[24];
#pragma unroll
      for (int g = 0; g < 24; ++g) {
        float a = ssb[g];
#pragma unroll
        for (int jj = 0; jj < 8; ++jj) a = fmaf(ssw[g * 8 + jj], h[jj], a);
        gh[g] = a;
      }
#pragma unroll
      for (int jj = 0; jj < 8; ++jj) {
        float rg = sigmf(gisb[t][sk][jj] + gh[jj]);
        float zg = sigmf(gisb[t][sk][8 + jj] + gh[8 + jj]);
        float ng = tanh_f(gisb[t][sk][16 + jj] + rg * gh[16 + jj]);
        h[jj] = (1.f - zg) * ng + zg * h[jj];
      }
    }
#pragma unroll
    for (int jj = 0; jj < 8; ++jj) hsbL[sk * 8 + jj] = h[jj];
  }
  __syncthreads();

  // ---- Phase D: final linear + highway ----
  int m = tid;
  if (m < Mn) {
    float a = lb[m];
    const float* wr = lw + (size_t)m * 320;
    for (int c = 0; c < 128; ++c) a = fmaf(hfL[c], wr[c], a);
    for (int c = 0; c < 192; ++c) a = fmaf(hsbL[c], wr[128 + c], a);
    float zv = hwb[0];
    const float* xrr = xr + ((size_t)n * Pn + (Pn - HWn)) * Mn + m;
#pragma unroll
    for (int k = 0; k < HWn; ++k) zv = fmaf(xrr[(size_t)k * Mn], shw[k], zv);
    out[(size_t)n * Mn + m] = a + zv;
  }
}

extern "C" void kernel_launch(void* const* d_in, const int* in_sizes, int n_in,
                              void* d_out, int out_size, void* d_ws, size_t ws_size,
                              hipStream_t stream) {
  const float* x = (const float*)d_in[0];
  const float* tw1 = (const float*)d_in[1];
  const float* tb1 = (const float*)d_in[2];
  const float* tw2 = (const float*)d_in[3];
  const float* tb2 = (const float*)d_in[4];
  const float* c1w = (const float*)d_in[5];
  const float* c1b = (const float*)d_in[6];
  const float* g1wih = (const float*)d_in[7];
  const float* g1whh = (const float*)d_in[8];
  const float* g1bih = (const float*)d_in[9];
  const float* g1bhh = (const float*)d_in[10];
  const float* gswih = (const float*)d_in[11];
  const float* gswhh = (const float*)d_in[12];
  const float* gsbih = (const float*)d_in[13];
  const float* gsbhh = (const float*)d_in[14];
  const float* l1w = (const float*)d_in[15];
  const float* l1b = (const float*)d_in[16];
  const float* hww = (const float*)d_in[17];
  const float* hwb = (const float*)d_in[18];
  float* out = (float*)d_out;

  // ---------- workspace plan ----------
  const size_t Ah = 17891328ull, Bh = 17891328ull, Ch = 17203200ull;  // halves per plane
  f16* Aq = (f16*)d_ws;
  f16* Bq = Aq + Ah;
  f16* Cq = Bq + Bh;
  f16* Wl1 = Cq + Ch;                      // 16*5*21*6144 = 10,321,920 halves
  f16* Wl2 = Wl1 + 10321920ull;            // 16*3*21*6144 = 6,193,152 halves
  f16* Wc2 = (f16*)(Wl2 + 6193152ull);     // conv2d f16 weight slab (258,048 halves)
  f16* Wgi = Wc2 + 258048ull;              // gru1 wih f16 slab (49,152 halves)
  float* giA = (float*)(Wl2 + 6193152ull) + 246528ull;  // 18,382,848 floats
  // post-tree aliases (new schedule, alias-checked):
  float* XR = (float*)Aq;                  // fp32 XR spans Aq+Bq (63.1 MB <= 71.6 MB)
  f16* Cch = Cq;                           // f16 conv2d output (12.25 MB)
  f16* XRh = Wl1;                          // fp16 XR (B*P*Mp halves == Wl1+Wl2)

  // region schedule (deint fused into conv<3,2>): per level
  f16* EO[3] = {Aq, Bq, Cq};
  f16* S1[3] = {Bq, Cq, Aq};
  f16* CD[3] = {Cq, Aq, Bq};
  f16* S3[3] = {Aq, Bq, Aq};
  f16* EUF = Cq;                           // final EU (L2, normal layout)
  const int WC0[3] = {0, 1, 2}, WC1[3] = {0, 3, 1}, WC2[3] = {0, 0, 1};

  repack_c2w<<<dim3(1008), 256, 0, stream>>>(c1w, Wc2);
  repack_giw<<<dim3(192), 256, 0, stream>>>(g1wih, Wgi);

  for (int L = 0; L < 3; ++L) {
    int NL = 1 << L;
    int Th = 96 >> L;
    int Z = 2 * NL;
    long zsEO = (long)Bn * Th * Mp;
    long zsS1 = (long)Bn * (Th + 2) * Mp;
    repack_w<<<dim3(24, 5 * 21, NL * 4), 256, 0, stream>>>(tw1, Wl1, 5, WC0[L], WC1[L], WC2[L]);
    repack_w<<<dim3(24, 3 * 21, NL * 4), 256, 0, stream>>>(tw2, Wl2, 3, WC0[L], WC1[L], WC2[L]);
    if (L == 0)
      deint_k<<<dim3(Bn, Th, 2), 256, 0, stream>>>(x, EO[0], Th);
    int ty1 = (Th + 2 + 31) / 32, ty2 = (Th + 31) / 32;
    conv_mfma<5, 0><<<dim3(64, ty1, Z), 512, 0, stream>>>(
        EO[L], zsEO, Th, Wl1, WC0[L], WC1[L], WC2[L], 0, tb1,
        nullptr, 0, S1[L], zsS1, Th + 2, 0);
    conv_mfma<3, 1><<<dim3(64, ty2, Z), 512, 0, stream>>>(
        S1[L], zsS1, Th + 2, Wl2, WC0[L], WC1[L], WC2[L], 0, tb2,
        EO[L], zsEO, CD[L], zsEO, Th, 0);
    conv_mfma<5, 0><<<dim3(64, ty1, Z), 512, 0, stream>>>(
        CD[L], zsEO, Th, Wl1, WC0[L], WC1[L], WC2[L], 2, tb1,
        nullptr, 0, S3[L], zsS1, Th + 2, 0);
    if (L < 2) {
      // fused deint: write child EO planes directly (2Z planes, Th/2 rows)
      conv_mfma<3, 2><<<dim3(64, ty2, Z), 512, 0, stream>>>(
          S3[L], zsS1, Th + 2, Wl2, WC0[L], WC1[L], WC2[L], 2, tb2,
          CD[L], zsEO, EO[L + 1], 0, Th, 1);
    } else {
      conv_mfma<3, 2><<<dim3(64, ty2, Z), 512, 0, stream>>>(
          S3[L], zsS1, Th + 2, Wl2, WC0[L], WC1[L], WC2[L], 2, tb2,
          CD[L], zsEO, EUF, zsEO, Th, 0);
    }
  }

  combine_k<<<dim3(Bn, Pn), 256, 0, stream>>>(x, EUF, XR, XRh);

  conv2d_mfma<<<dim3(Bn / 32, (Ln + 3) / 4), 256, 0, stream>>>(XRh, Wc2, c1b, Cch);
  gemm_gi<<<dim3((Ln * Bn) / 128), 512, 0, stream>>>(Cch, Wgi, g1bih, giA);
  tail_k<<<dim3(Bn), 512, 0, stream>>>(giA, g1whh, g1bhh, Cch, gswih, gsbih,
                                       gswhh, gsbhh, l1w, l1b, XR, hww, hwb, out);
}